// Round 1
// baseline (1098.354 us; speedup 1.0000x reference)
//
#include <hip/hip_runtime.h>
#include <math.h>

#define D_VOCAB 50257
#define D_MODEL 768
#define DM4 (D_MODEL / 4)      // 192 float4 per output row
#define FIND_BLOCKS 2048
#define FIND_THREADS 256
#define BATCH 8                // uint4 loads in flight per lane per sweep

// Phase 1: pure streaming sweep of the whole one-hot buffer.
// No per-row serial chains: 2048x256 threads grid-stride with 8 independent
// 16B loads in flight per lane -> BW-bound, ~823 MB at ~6.2 TB/s.
// Exactly one nonzero per row, so the finder does a plain (race-free) store.
// A uint4 may straddle a row boundary (50257 is odd) and can legitimately
// contain two different rows' ones -> each component resolved independently.
__global__ __launch_bounds__(FIND_THREADS) void find_cols(
    const uint4* __restrict__ tok4,
    unsigned*             colbuf,      // col index per row (stride below)
    unsigned              colstride,   // 1 (workspace) or 768 (stash in out)
    unsigned              total_f)     // n_rows * D_VOCAB, total floats
{
    const unsigned total4 = total_f >> 2;          // exact when n_rows%4==0
    const unsigned stride = gridDim.x * FIND_THREADS;
    const unsigned tid    = blockIdx.x * FIND_THREADS + threadIdx.x;

    for (unsigned p0 = tid; p0 < total4; p0 += stride * BATCH) {
        uint4 v[BATCH];
        #pragma unroll
        for (int k = 0; k < BATCH; ++k) {
            unsigned p = p0 + (unsigned)k * stride;
            v[k] = (p < total4) ? tok4[p] : make_uint4(0u, 0u, 0u, 0u);
        }
        #pragma unroll
        for (int k = 0; k < BATCH; ++k) {
            if (v[k].x | v[k].y | v[k].z | v[k].w) {   // rare: 4096 hits / 51M loads
                const unsigned f = (p0 + (unsigned)k * stride) * 4u;
                #pragma unroll
                for (int c = 0; c < 4; ++c) {
                    const unsigned vc = (c == 0) ? v[k].x : (c == 1) ? v[k].y
                                      : (c == 2) ? v[k].z : v[k].w;
                    if (vc) {
                        const unsigned fc  = f + (unsigned)c;
                        if (fc < total_f) {
                            const unsigned row = fc / (unsigned)D_VOCAB;  // magic-mul
                            const unsigned col = fc - row * (unsigned)D_VOCAB;
                            colbuf[row * colstride] = col;
                        }
                    }
                }
            }
        }
    }
}

// Phase 2: one wave per output row; gather W[col,:]*sqrt(768)+bias.
// ~25 MB total traffic, coalesced 1 KB per wave-instruction.
__global__ __launch_bounds__(256) void gather_rows(
    const unsigned*       colbuf,
    unsigned              colstride,
    const float4* __restrict__ W4,
    const float4* __restrict__ b4,
    float4*               out4,        // no restrict: may alias colbuf fallback
    unsigned              n_rows)
{
    const unsigned wave = blockIdx.x * 4u + (threadIdx.x >> 6);
    if (wave >= n_rows) return;
    const unsigned lane = threadIdx.x & 63u;

    unsigned col = colbuf[wave * colstride];   // wave-uniform broadcast load
    if (col >= (unsigned)D_VOCAB) col = 0;     // defensive clamp (never expected)

    const float scale = 27.712812921102035f;   // sqrt(768)
    #pragma unroll
    for (int j = 0; j < 3; ++j) {
        const unsigned d = lane + 64u * (unsigned)j;
        const float4 w = W4[col * (unsigned)DM4 + d];
        const float4 b = b4[d];
        float4 o;
        o.x = fmaf(w.x, scale, b.x);
        o.y = fmaf(w.y, scale, b.y);
        o.z = fmaf(w.z, scale, b.z);
        o.w = fmaf(w.w, scale, b.w);
        out4[wave * (unsigned)DM4 + d] = o;
    }
}

extern "C" void kernel_launch(void* const* d_in, const int* in_sizes, int n_in,
                              void* d_out, int out_size, void* d_ws, size_t ws_size,
                              hipStream_t stream) {
    const float* tokens  = (const float*)d_in[0];   // [B*P, V] fp32 one-hot
    const float* weights = (const float*)d_in[1];   // [V, D] fp32
    const float* bias    = (const float*)d_in[2];   // [D] fp32
    float* out = (float*)d_out;                     // [B*P, D] fp32

    const unsigned n_rows  = (unsigned)(out_size / D_MODEL);       // 4096
    const unsigned total_f = n_rows * (unsigned)D_VOCAB;           // 205,852,672

    // Column-index buffer: workspace if available, else stash at out[row*768]
    // (gather reads it before overwriting that row; safe within the wave's
    // program order since the load precedes the stores).
    unsigned* colbuf;
    unsigned  colstride;
    if (d_ws != nullptr && ws_size >= (size_t)n_rows * sizeof(unsigned)) {
        colbuf    = (unsigned*)d_ws;
        colstride = 1u;
    } else {
        colbuf    = (unsigned*)out;
        colstride = (unsigned)D_MODEL;   // out[row*768]
    }

    find_cols<<<FIND_BLOCKS, FIND_THREADS, 0, stream>>>(
        (const uint4*)tokens, colbuf, colstride, total_f);

    const unsigned gather_blocks = (n_rows + 3u) / 4u;             // 4 waves/block
    gather_rows<<<gather_blocks, 256, 0, stream>>>(
        colbuf, colstride, (const float4*)weights, (const float4*)bias,
        (float4*)out, n_rows);
}

// Round 3
// 1024.622 us; speedup vs baseline: 1.0720x; 1.0720x over previous
//
#include <hip/hip_runtime.h>
#include <math.h>

#define D_VOCAB 50257
#define D_MODEL 768
#define DM4 (D_MODEL / 4)   // 192 float4 per output row
#define CH 8                // uint4 loads in flight per thread per chunk (32 KB/block-chunk)
#define SENT 0xFFFFFFFFu

// ONE kernel, block-per-row, no workspace, no second launch.
//  - Block b scans row b's one-hot stripe in 32 KB chunks: 8 independent
//    coalesced uint4 loads per thread (full MLP), then a block-wide
//    found-check via LDS flag. Early exit saves ~42% of the scan on average.
//  - 4096 blocks x 256 threads (8 blocks/CU at <=64 VGPR) gives enough
//    co-resident blocks to hide per-chunk HBM latency across blocks --
//    the parallelism the old wave-per-row version lacked.
//  - Two __syncthreads() per chunk make the break decision uniform and
//    race-free (write epoch | barrier | read epoch | barrier). s_col is
//    written at most ONCE per block (exactly one 1.0 per row, pad elements
//    from neighbor rows are range-filtered), so no reset is needed.
//  - Gather fused: threads 0..191 write one float4 of W[col,:]*sqrt(768)+b.
// Correctness notes:
//  - Row base rb (float units) is only 4B-aligned (50257 odd); scan starts
//    at floor(rb/4) in float4 units. Pad elements belonging to neighbor
//    rows are filtered by the [rb, re) range check.
//  - One-hot values are exactly 0.0f or 1.0f -> integer nonzero test exact.
__global__ __launch_bounds__(256) void embed_block(
    const uint4*  __restrict__ tok4,
    const float4* __restrict__ W4,
    const float4* __restrict__ b4,
    float4*       __restrict__ out4,
    unsigned n_rows)
{
    const unsigned row = blockIdx.x;
    if (row >= n_rows) return;                      // uniform per block
    const unsigned tid = threadIdx.x;

    const unsigned rb = row * (unsigned)D_VOCAB;    // row start, float units
    const unsigned re = rb + (unsigned)D_VOCAB;     // row end (exclusive)
    const unsigned a4 = rb >> 2;                    // aligned start, float4 units
    const unsigned e4 = (re + 3u) >> 2;             // aligned end,   float4 units

    __shared__ unsigned s_col;
    if (tid == 0) s_col = SENT;
    __syncthreads();

    unsigned col = 0;
    for (unsigned base = a4; base < e4; base += 256u * CH) {
        // ---- issue all CH loads before any use (per-thread MLP) ----
        uint4 v[CH];
        #pragma unroll
        for (int k = 0; k < CH; ++k) {
            const unsigned p = base + (unsigned)k * 256u + tid;
            v[k] = (p < e4) ? tok4[p] : make_uint4(0u, 0u, 0u, 0u);
        }
        // ---- per-thread hit detection (range-filtered to own row) ----
        unsigned hit = SENT;
        #pragma unroll
        for (int k = 0; k < CH; ++k) {
            if (v[k].x | v[k].y | v[k].z | v[k].w) {     // rare
                const unsigned f = (base + (unsigned)k * 256u + tid) * 4u;
                if (v[k].x && f + 0u >= rb && f + 0u < re) hit = f + 0u - rb;
                if (v[k].y && f + 1u >= rb && f + 1u < re) hit = f + 1u - rb;
                if (v[k].z && f + 2u >= rb && f + 2u < re) hit = f + 2u - rb;
                if (v[k].w && f + 3u >= rb && f + 3u < re) hit = f + 3u - rb;
            }
        }
        if (hit != SENT) s_col = hit;    // at most one writer per block, ever
        __syncthreads();                 // write epoch -> read epoch
        const unsigned sc = s_col;       // uniform view
        __syncthreads();                 // read epoch -> next write epoch
        if (sc != SENT) { col = sc; break; }   // uniform break
    }

    // ---- fused gather: 192 float4, threads 0..191 (3 full waves) ----
    if (tid < (unsigned)DM4) {
        const float scale = 27.712812921102035f;   // sqrt(768)
        const float4 w = W4[col * (unsigned)DM4 + tid];
        const float4 b = b4[tid];
        float4 o;
        o.x = fmaf(w.x, scale, b.x);
        o.y = fmaf(w.y, scale, b.y);
        o.z = fmaf(w.z, scale, b.z);
        o.w = fmaf(w.w, scale, b.w);
        out4[row * (unsigned)DM4 + tid] = o;
    }
}

extern "C" void kernel_launch(void* const* d_in, const int* in_sizes, int n_in,
                              void* d_out, int out_size, void* d_ws, size_t ws_size,
                              hipStream_t stream) {
    const float* tokens  = (const float*)d_in[0];   // [B*P, V] fp32 one-hot
    const float* weights = (const float*)d_in[1];   // [V, D] fp32
    const float* bias    = (const float*)d_in[2];   // [D] fp32
    float* out = (float*)d_out;                     // [B*P, D] fp32

    const unsigned n_rows = (unsigned)(out_size / D_MODEL);   // 4096
    embed_block<<<n_rows, 256, 0, stream>>>((const uint4*)tokens,
                                            (const float4*)weights,
                                            (const float4*)bias,
                                            (float4*)out, n_rows);
}